// Round 2
// baseline (189.861 us; speedup 1.0000x reference)
//
#include <hip/hip_runtime.h>
#include <hip/hip_fp16.h>

#define N_ITEMS 100000
#define HID 128
#define NNZ_T 1600000
#define RP_BLOCKS 391              // ceil(100001/256) binary-search blocks (placed FIRST)
#define GB_BLOCKS 1563             // ceil(100000/64) gemm blocks
#define SPMM_BLOCKS 6250           // 25000 row-quads / 4 waves per block

typedef unsigned short ushort_t;
typedef unsigned int uint_t;
typedef short bf16x8 __attribute__((ext_vector_type(8)));
typedef float f32x4 __attribute__((ext_vector_type(4)));
typedef _Float16 h2_t __attribute__((ext_vector_type(2)));

static __device__ __forceinline__ ushort_t f32_to_bf16(float f) {
    uint_t u = __float_as_uint(f);
    uint_t r = (u + 0x7FFFu + ((u >> 16) & 1u)) >> 16;   // RNE
    return (ushort_t)r;
}

// w, h are half2 bit-patterns; returns acc + w.lo*h.lo + w.hi*h.hi in f32.
static __device__ __forceinline__ float fdot2w(uint_t w, uint_t h, float acc) {
#if __has_builtin(__builtin_amdgcn_fdot2)
    return __builtin_amdgcn_fdot2(__builtin_bit_cast(h2_t, w),
                                  __builtin_bit_cast(h2_t, h), acc, false);
#else
    __half2 hv = *(__half2*)&h; __half2 wv = *(__half2*)&w;
    return acc + __low2float(wv) * __low2float(hv)
               + __high2float(wv) * __high2float(hv);
#endif
}

// A[0..7] += v * halves of U; WLO = half2(v,0), WHI = half2(0,v) bit patterns.
#define DOT8(A, U, WLO, WHI) do {                                       \
    A[0] = fdot2w(WLO, (U).x, A[0]); A[1] = fdot2w(WHI, (U).x, A[1]);   \
    A[2] = fdot2w(WLO, (U).y, A[2]); A[3] = fdot2w(WHI, (U).y, A[3]);   \
    A[4] = fdot2w(WLO, (U).z, A[4]); A[5] = fdot2w(WHI, (U).z, A[5]);   \
    A[6] = fdot2w(WLO, (U).w, A[6]); A[7] = fdot2w(WHI, (U).w, A[7]);   \
} while (0)

// === K1: blocks [0,RP_BLOCKS) build row_ptr; blocks [RP_BLOCKS..) do the GEMM,
// staging W f32->bf16 into LDS (XOR-swizzled so ds_read_b128 is 2-way = free).
__global__ __launch_bounds__(256) void prep_gemm(
    const float* __restrict__ X, const float* __restrict__ W,
    const float* __restrict__ bias, const int* __restrict__ rows,
    ushort_t* __restrict__ S, int* __restrict__ row_ptr) {
    if (blockIdx.x < RP_BLOCKS) {
        int r = blockIdx.x * 256 + threadIdx.x;
        if (r > N_ITEMS) return;
        int lo = 0, hi = NNZ_T;
        while (lo < hi) {                       // lower_bound(rows, r), rows sorted
            int mid = (lo + hi) >> 1;
            if (rows[mid] < r) lo = mid + 1; else hi = mid;
        }
        row_ptr[r] = lo;
        return;
    }

    __shared__ ushort_t Wl[HID * HID];          // 32 KB bf16, swizzled
    {
        const int t = threadIdx.x;
        const float4* Wf = (const float4*)W;
#pragma unroll
        for (int j = 0; j < 8; ++j) {
            const int gblk = j * 256 + t;       // 16B granule id, 0..2047
            float4 w0 = Wf[gblk * 2];
            float4 w1 = Wf[gblk * 2 + 1];
            bf16x8 v;
            v[0] = (short)f32_to_bf16(w0.x); v[1] = (short)f32_to_bf16(w0.y);
            v[2] = (short)f32_to_bf16(w0.z); v[3] = (short)f32_to_bf16(w0.w);
            v[4] = (short)f32_to_bf16(w1.x); v[5] = (short)f32_to_bf16(w1.y);
            v[6] = (short)f32_to_bf16(w1.z); v[7] = (short)f32_to_bf16(w1.w);
            const int ps = (gblk * 8) ^ (((gblk >> 4) & 7) << 3);  // phys short idx
            *(bf16x8*)&Wl[ps] = v;
        }
    }
    __syncthreads();

    const int lane = threadIdx.x & 63;
    const int wave = threadIdx.x >> 6;
    const int m = lane & 15;
    const int q = lane >> 4;
    const int row0 = (blockIdx.x - RP_BLOCKS) * 64 + wave * 16;

    int arow = row0 + m;
    if (arow >= N_ITEMS) arow = N_ITEMS - 1;    // clamp (stores guarded)

    const int swz = (m & 7) << 3;               // row&7 == m&7 for row = nt*16+m
    f32x4 acc[8] = {};

#pragma unroll
    for (int kb = 0; kb < 4; ++kb) {
        const int k0 = kb * 32 + q * 8;
        float4 a0 = *(const float4*)&X[(size_t)arow * HID + k0];
        float4 a1 = *(const float4*)&X[(size_t)arow * HID + k0 + 4];
        bf16x8 xf;
        xf[0] = (short)f32_to_bf16(a0.x); xf[1] = (short)f32_to_bf16(a0.y);
        xf[2] = (short)f32_to_bf16(a0.z); xf[3] = (short)f32_to_bf16(a0.w);
        xf[4] = (short)f32_to_bf16(a1.x); xf[5] = (short)f32_to_bf16(a1.y);
        xf[6] = (short)f32_to_bf16(a1.z); xf[7] = (short)f32_to_bf16(a1.w);
#pragma unroll
        for (int nt = 0; nt < 8; ++nt) {
            const bf16x8 wf = *(const bf16x8*)&Wl[((nt * 16 + m) * HID + k0) ^ swz];
            acc[nt] = __builtin_amdgcn_mfma_f32_16x16x32_bf16(wf, xf, acc[nt], 0, 0, 0);
        }
    }

    const int srow = row0 + m;
    const bool ok = srow < N_ITEMS;
#pragma unroll
    for (int nt = 0; nt < 8; ++nt) {
        const int c0 = nt * 16 + q * 4;         // 4 consecutive out cols
        float4 bv = *(const float4*)&bias[c0];
        ushort_t h0 = __half_as_ushort(__float2half(acc[nt][0] + bv.x));
        ushort_t h1 = __half_as_ushort(__float2half(acc[nt][1] + bv.y));
        ushort_t h2 = __half_as_ushort(__float2half(acc[nt][2] + bv.z));
        ushort_t h3 = __half_as_ushort(__float2half(acc[nt][3] + bv.w));
        uint2 pk;
        pk.x = (uint_t)h0 | ((uint_t)h1 << 16);
        pk.y = (uint_t)h2 | ((uint_t)h3 << 16);
        if (ok) *(uint2*)&S[(size_t)srow * HID + c0] = pk;
    }
}

// === K2: out[row] = sum vals*S[cols] (fp16 S, f32 accumulate via v_dot2_f32_f16).
// FLAT scheme: each wave owns 4 consecutive rows; their CSR segments are one
// contiguous edge run [ptr[4w], ptr[4w+4]). Windows of 32 edges regardless of
// row boundaries (padding only in the final window: ~1.88M slot-gathers vs
// 2.69M for per-row 16-slot windows). Each 4-edge group (one gather instr,
// g=0..3) is routed to the owning row's f32 accumulator via wave-uniform
// branches; boundary-straddling groups (~16%) take a masked all-rows path.
// Non-persistent (one quad per wave) — round 1 showed persistence costs
// occupancy. Empty rows -> 0. No atomics.
__global__ __launch_bounds__(256) void spmm_csr(
    const int* __restrict__ cols, const float* __restrict__ vals,
    const int* __restrict__ row_ptr, const ushort_t* __restrict__ S,
    float* __restrict__ out) {
    const int lane = threadIdx.x & 63;
    const int g = lane >> 4;                    // edge slot within a quad (0..3)
    const int l = lane & 15;                    // column octet: cols 8*l .. 8*l+7
    const int wid = blockIdx.x * 4 + (threadIdx.x >> 6);
    const int r0 = wid * 4;                     // rows r0 .. r0+3
    if (r0 >= N_ITEMS) return;

    const int4 p = *(const int4*)&row_ptr[r0];  // 16B aligned (r0 % 4 == 0)
    const int pend = row_ptr[r0 + 4];
    const int b1 = p.y, b2 = p.z, b3 = p.w;

    float a0[8] = {}, a1x[8] = {}, a2x[8] = {}, a3[8] = {};

    for (int base = p.x; base < pend; base += 32) {
        // lanes 0-31 load the window's 32 contiguous (col,val); 32-63 duplicate
        const int idx = base + (lane & 31);
        const int cidx = min(idx, pend - 1);    // clamp (pend > base >= 0 here)
        const int c_l = cols[cidx];
        const float v_l = (idx < pend) ? vals[cidx] : 0.f;

        int ct[8]; float vt[8];
#pragma unroll
        for (int t = 0; t < 8; ++t) {           // slot s = 4t+g, source lane < 32
            ct[t] = __shfl(c_l, 4 * t + g, 64);
            vt[t] = __shfl(v_l, 4 * t + g, 64);
        }
        uint4 u[8];
#pragma unroll
        for (int t = 0; t < 8; ++t)             // 8 quad-gathers in flight
            u[t] = *(const uint4*)&S[(size_t)ct[t] * HID + 8 * l];

#pragma unroll
        for (int t = 0; t < 8; ++t) {
            const int s_lo = base + 4 * t;
            const int s_hi = s_lo + 3;
            if (s_lo >= pend) continue;         // pure-padding group
            const uint_t vh = (uint_t)__half_as_ushort(__float2half(vt[t]));
            const uint_t wlo = vh;              // half2(v, 0)
            const uint_t whi = vh << 16;        // half2(0, v)
            if (s_lo >= b3)                   { DOT8(a3, u[t], wlo, whi); }   // pads v=0
            else if (s_hi < b1)               { DOT8(a0, u[t], wlo, whi); }
            else if (s_lo >= b1 && s_hi < b2) { DOT8(a1x, u[t], wlo, whi); }
            else if (s_lo >= b2 && s_hi < b3) { DOT8(a2x, u[t], wlo, whi); }
            else {                              // straddles a row boundary
                const int s = s_lo + g;
                const bool c0 = (s < b1);
                const bool c1 = (s >= b1) && (s < b2);
                const bool c2 = (s >= b2) && (s < b3);
                const bool c3 = (s >= b3);
                const uint_t w0l = c0 ? wlo : 0u, w0h = c0 ? whi : 0u;
                const uint_t w1l = c1 ? wlo : 0u, w1h = c1 ? whi : 0u;
                const uint_t w2l = c2 ? wlo : 0u, w2h = c2 ? whi : 0u;
                const uint_t w3l = c3 ? wlo : 0u, w3h = c3 ? whi : 0u;
                DOT8(a0, u[t], w0l, w0h);
                DOT8(a1x, u[t], w1l, w1h);
                DOT8(a2x, u[t], w2l, w2h);
                DOT8(a3, u[t], w3l, w3h);
            }
        }
    }

    // cross-group reduce: partials for each row live in all 4 g-groups
#pragma unroll
    for (int e = 0; e < 8; ++e) {
        a0[e] += __shfl_xor(a0[e], 16, 64);  a0[e] += __shfl_xor(a0[e], 32, 64);
        a1x[e] += __shfl_xor(a1x[e], 16, 64); a1x[e] += __shfl_xor(a1x[e], 32, 64);
        a2x[e] += __shfl_xor(a2x[e], 16, 64); a2x[e] += __shfl_xor(a2x[e], 32, 64);
        a3[e] += __shfl_xor(a3[e], 16, 64);  a3[e] += __shfl_xor(a3[e], 32, 64);
    }
    // group g stores row r0+g (all rows valid: N_ITEMS % 4 == 0)
    float* po = &out[(size_t)(r0 + g) * HID + 8 * l];
    if (g == 0) {
        *(float4*)po       = make_float4(a0[0], a0[1], a0[2], a0[3]);
        *(float4*)(po + 4) = make_float4(a0[4], a0[5], a0[6], a0[7]);
    } else if (g == 1) {
        *(float4*)po       = make_float4(a1x[0], a1x[1], a1x[2], a1x[3]);
        *(float4*)(po + 4) = make_float4(a1x[4], a1x[5], a1x[6], a1x[7]);
    } else if (g == 2) {
        *(float4*)po       = make_float4(a2x[0], a2x[1], a2x[2], a2x[3]);
        *(float4*)(po + 4) = make_float4(a2x[4], a2x[5], a2x[6], a2x[7]);
    } else {
        *(float4*)po       = make_float4(a3[0], a3[1], a3[2], a3[3]);
        *(float4*)(po + 4) = make_float4(a3[4], a3[5], a3[6], a3[7]);
    }
}

extern "C" void kernel_launch(void* const* d_in, const int* in_sizes, int n_in,
                              void* d_out, int out_size, void* d_ws, size_t ws_size,
                              hipStream_t stream) {
    const float* X    = (const float*)d_in[0];
    const int*   rows = (const int*)  d_in[1];
    const int*   cols = (const int*)  d_in[2];
    const float* vals = (const float*)d_in[3];
    const float* W    = (const float*)d_in[4];
    const float* bias = (const float*)d_in[5];
    float* out = (float*)d_out;

    ushort_t* S       = (ushort_t*)d_ws;                    // 25.6 MB (fp16)
    int*      row_ptr = (int*)(S + (size_t)N_ITEMS * HID);  // 400 KB

    prep_gemm<<<RP_BLOCKS + GB_BLOCKS, 256, 0, stream>>>(X, W, bias, rows, S, row_ptr);
    spmm_csr<<<SPMM_BLOCKS, 256, 0, stream>>>(cols, vals, row_ptr, S, out);
}